// Round 6
// baseline (1599.798 us; speedup 1.0000x reference)
//
#include <hip/hip_runtime.h>
#include <stdint.h>

typedef __attribute__((ext_vector_type(8))) _Float16 half8;
typedef __attribute__((ext_vector_type(4))) float f32x4;
typedef __attribute__((ext_vector_type(4))) uint32_t uint4v;

#define LR 0.1f
#define BLOCK 512
#define PERM __builtin_amdgcn_perm

// LDS byte offsets
// WFRAG: [9 layers][2 dir][3 tiles][2 ks][64 lanes][16B] = 110592
#define WOUTP_OFF  110592   // pred B-frags: [2 ks][64][16B] = 2048
#define WOUTT_OFF  112640   // td10 B-frags: [3 tiles][64][16B] = 3072
#define BH_OFF_B   115712   // bh f32: 9*48*4 = 1728
#define BOUT_OFF_B 117440   // bout f32: 64
#define VT_OFF_B   117504   // per-wave transpose tile: 864 u32 = 3456B * 8 waves
#define VT_STRIDE  3456
#define LDS_BYTES  (VT_OFF_B + 8*VT_STRIDE)   // 145152

extern __shared__ unsigned char smem[];

#define F16BITS(VAL) ((uint32_t)__builtin_bit_cast(unsigned short, (_Float16)(VAL)))

// pack f32 -> (f16 hi << 16) | f16 lo  (2-term split)
#define PACK_SPLIT(VAL, W) do { \
  float _v0 = (VAL); \
  _Float16 _hh = (_Float16)_v0; \
  float _hf = (float)_hh; \
  W = (F16BITS(_v0 - _hf)) | ((uint32_t)__builtin_bit_cast(unsigned short, _hh) << 16); \
} while(0)

// build hi-half / lo-half gathered words from 8 packed u32s (SSA only, no allocas)
#define GATHER_HI(WA, WB, HU) do { \
  HU[0] = PERM(WA[1], WA[0], 0x07060302u); \
  HU[1] = PERM(WA[3], WA[2], 0x07060302u); \
  HU[2] = PERM(WB[1], WB[0], 0x07060302u); \
  HU[3] = PERM(WB[3], WB[2], 0x07060302u); \
} while(0)
#define GATHER_LO(WA, WB, LU) do { \
  LU[0] = PERM(WA[1], WA[0], 0x05040100u); \
  LU[1] = PERM(WA[3], WA[2], 0x05040100u); \
  LU[2] = PERM(WB[1], WB[0], 0x05040100u); \
  LU[3] = PERM(WB[3], WB[2], 0x05040100u); \
} while(0)

// 48x48 matvec for 16 samples via MFMA. SRC/DST: float[12] in C-layout
// (idx = tile*4 + r ; value of sample 4*bq+r, comp n+16*tile).
// WFB: byte base of B-frag storage (3 tiles x 2 ks x 64 lanes x 16B).
// SPLIT: 1 = 2-term f16 split A (accurate), 0 = single f16 A (LR-damped paths).
// B-frags + biases are preloaded FIRST so their latency hides under the pack VALU.
#define MV48(SRC, WFB, BIASOFF, HASBIAS, SPLIT, DST) do { \
  half8 _B00 = *(const half8*)(smem + (WFB) + 0*1024 + lane*16); \
  half8 _B01 = *(const half8*)(smem + (WFB) + 1*1024 + lane*16); \
  half8 _B10 = *(const half8*)(smem + (WFB) + 2*1024 + lane*16); \
  half8 _B11 = *(const half8*)(smem + (WFB) + 3*1024 + lane*16); \
  half8 _B20 = *(const half8*)(smem + (WFB) + 4*1024 + lane*16); \
  half8 _B21 = *(const half8*)(smem + (WFB) + 5*1024 + lane*16); \
  float _bv0 = (HASBIAS) ? bhf[(BIASOFF) + n]      : 0.f; \
  float _bv1 = (HASBIAS) ? bhf[(BIASOFF) + n + 16] : 0.f; \
  float _bv2 = (HASBIAS) ? bhf[(BIASOFF) + n + 32] : 0.f; \
  _Pragma("unroll") \
  for (int _t = 0; _t < 3; ++_t) { \
    _Pragma("unroll") \
    for (int _r = 0; _r < 4; ++_r) { \
      uint32_t _w; \
      if (SPLIT) { PACK_SPLIT(SRC[_t*4+_r], _w); } \
      else { _w = F16BITS(SRC[_t*4+_r]) << 16; } \
      vtu[(4*bq+_r)*52 + n + 16*_t] = _w; \
    } \
  } \
  __builtin_amdgcn_fence(__ATOMIC_ACQ_REL, "wavefront"); \
  half8 _Ah0, _Ah1, _Al0, _Al1; \
  { \
    const uint32_t* _vp = vtu + n*52 + bq*8; \
    uint4v _wa = *(const uint4v*)_vp; \
    uint4v _wb = *(const uint4v*)(_vp + 4); \
    uint4v _hu; GATHER_HI(_wa, _wb, _hu); _Ah0 = __builtin_bit_cast(half8, _hu); \
    if (SPLIT) { uint4v _lu; GATHER_LO(_wa, _wb, _lu); _Al0 = __builtin_bit_cast(half8, _lu); } \
    _vp = vtu + n*52 + 32 + bq*8; \
    _wa = *(const uint4v*)_vp; \
    _wb = *(const uint4v*)(_vp + 4); \
    uint4v _hu2; GATHER_HI(_wa, _wb, _hu2); _Ah1 = __builtin_bit_cast(half8, _hu2); \
    if (SPLIT) { uint4v _lu2; GATHER_LO(_wa, _wb, _lu2); _Al1 = __builtin_bit_cast(half8, _lu2); } \
  } \
  { \
    f32x4 _acc = { _bv0, _bv0, _bv0, _bv0 }; \
    _acc = __builtin_amdgcn_mfma_f32_16x16x32_f16(_Ah0, _B00, _acc, 0, 0, 0); \
    if (SPLIT) _acc = __builtin_amdgcn_mfma_f32_16x16x32_f16(_Al0, _B00, _acc, 0, 0, 0); \
    _acc = __builtin_amdgcn_mfma_f32_16x16x32_f16(_Ah1, _B01, _acc, 0, 0, 0); \
    if (SPLIT) _acc = __builtin_amdgcn_mfma_f32_16x16x32_f16(_Al1, _B01, _acc, 0, 0, 0); \
    _Pragma("unroll") \
    for (int _r = 0; _r < 4; ++_r) DST[0*4+_r] = _acc[_r]; \
  } \
  { \
    f32x4 _acc = { _bv1, _bv1, _bv1, _bv1 }; \
    _acc = __builtin_amdgcn_mfma_f32_16x16x32_f16(_Ah0, _B10, _acc, 0, 0, 0); \
    if (SPLIT) _acc = __builtin_amdgcn_mfma_f32_16x16x32_f16(_Al0, _B10, _acc, 0, 0, 0); \
    _acc = __builtin_amdgcn_mfma_f32_16x16x32_f16(_Ah1, _B11, _acc, 0, 0, 0); \
    if (SPLIT) _acc = __builtin_amdgcn_mfma_f32_16x16x32_f16(_Al1, _B11, _acc, 0, 0, 0); \
    _Pragma("unroll") \
    for (int _r = 0; _r < 4; ++_r) DST[1*4+_r] = _acc[_r]; \
  } \
  { \
    f32x4 _acc = { _bv2, _bv2, _bv2, _bv2 }; \
    _acc = __builtin_amdgcn_mfma_f32_16x16x32_f16(_Ah0, _B20, _acc, 0, 0, 0); \
    if (SPLIT) _acc = __builtin_amdgcn_mfma_f32_16x16x32_f16(_Al0, _B20, _acc, 0, 0, 0); \
    _acc = __builtin_amdgcn_mfma_f32_16x16x32_f16(_Ah1, _B21, _acc, 0, 0, 0); \
    if (SPLIT) _acc = __builtin_amdgcn_mfma_f32_16x16x32_f16(_Al1, _B21, _acc, 0, 0, 0); \
    _Pragma("unroll") \
    for (int _r = 0; _r < 4; ++_r) DST[2*4+_r] = _acc[_r]; \
  } \
} while(0)

#define LAYER_STEP(I) do { \
  float _pre[12], _err[12], _me[12], _td[12]; \
  MV48(v[(I)-1], ((I)-1)*12288, ((I)-1)*48, 1, 1, _pre); \
  _Pragma("unroll") \
  for (int _q = 0; _q < 12; ++_q) { \
    float _rl = fmaxf(_pre[_q], 0.f); \
    _err[_q] = v[I][_q] - _rl; \
    _me[_q] = (_pre[_q] > 0.f) ? _err[_q] : 0.f; \
  } \
  MV48(_me, ((I)-1)*12288 + 6144, 0, 0, 0, _td); \
  _Pragma("unroll") \
  for (int _q = 0; _q < 12; ++_q) { \
    float _nv = v[(I)-1][_q] - LR*(ep[_q] - _td[_q]); \
    v[(I)-1][_q] = fminf(fmaxf(_nv, -10.f), 10.f); \
    ep[_q] = _err[_q]; \
  } \
} while(0)

#define FWD(I) do { \
  float _pre[12]; \
  MV48(v[(I)-1], ((I)-1)*12288, ((I)-1)*48, 1, 1, _pre); \
  _Pragma("unroll") \
  for (int _q = 0; _q < 12; ++_q) v[I][_q] = fmaxf(_pre[_q], 0.f); \
} while(0)

__global__ __launch_bounds__(BLOCK) __attribute__((amdgpu_waves_per_eu(1, 1)))
void pcnet_kernel(const float* __restrict__ x, const int* __restrict__ target,
                  const float* __restrict__ W0, const float* __restrict__ b0,
                  const float* __restrict__ Wh, const float* __restrict__ bh,
                  const float* __restrict__ Wout, const float* __restrict__ bout,
                  float* __restrict__ out)
{
    const int t = threadIdx.x;
    const int lane = t & 63;
    const int wv = t >> 6;
    float* ldsf = (float*)smem;
    const float* bhf = (const float*)(smem + BH_OFF_B);
    const float* boutf = (const float*)(smem + BOUT_OFF_B);

    const int bsamp0 = blockIdx.x*128 + wv*16;   // wave's first sample

    // ======== phase 0: a0 = relu(x@W0^T + b0), 4-lane-quarter mapping ========
    const int g = lane & 3, sloc = lane >> 2;
    const int bOld = bsamp0 + sloc;
    const int j0 = g*12;
    float acc0[12];
    #pragma unroll
    for (int jj = 0; jj < 12; jj++) acc0[jj] = b0[j0+jj];
    for (int ch = 0; ch < 7; ch++) {
        __syncthreads();
        for (int idx = t; idx < 112*48; idx += BLOCK) {
            int j = idx / 112, kl = idx - j*112;
            ldsf[kl*48 + j] = W0[j*784 + ch*112 + kl];
        }
        __syncthreads();
        const float* xb = x + (size_t)bOld*784 + ch*112;
        for (int k4 = 0; k4 < 112; k4 += 4) {
            float4 xv = *(const float4*)(xb + k4);
            float xs[4] = {xv.x, xv.y, xv.z, xv.w};
            #pragma unroll
            for (int f = 0; f < 4; f++) {
                const float* wr = &ldsf[(k4+f)*48 + j0];
                #pragma unroll
                for (int jj = 0; jj < 12; jj++) acc0[jj] = fmaf(wr[jj], xs[f], acc0[jj]);
            }
        }
    }

    // remap a0 -> C-layout via per-wave VT tile (f32 view)
    float* vtf = (float*)(smem + VT_OFF_B + wv*VT_STRIDE);
    uint32_t* vtu = (uint32_t*)(smem + VT_OFF_B + wv*VT_STRIDE);
    #pragma unroll
    for (int jj = 0; jj < 12; jj++) vtf[sloc*52 + j0 + jj] = fmaxf(acc0[jj], 0.f);
    __builtin_amdgcn_fence(__ATOMIC_ACQ_REL, "wavefront");

    const int bq = lane >> 4;    // 0..3: sample block in frag
    const int n  = lane & 15;    // col within tile
    float v[10][12], a0r[12];
    #pragma unroll
    for (int tt = 0; tt < 3; tt++)
        #pragma unroll
        for (int r = 0; r < 4; r++) {
            float val = vtf[(4*bq+r)*52 + n + 16*tt];
            a0r[tt*4+r] = val; v[0][tt*4+r] = val;
        }

    // zero VT pad columns 48..51 and tail pad (avoid NaN garbage in MFMA reads)
    vtu[(lane>>2)*52 + 48 + (lane&3)] = 0u;
    if (lane < 32) vtu[832 + lane] = 0u;

    __syncthreads();

    // ======== stage weight frags (f16, frag-order: conflict-free 16B/lane) ========
    for (int slot = t; slot < 6912; slot += BLOCK) {
        int L = slot / 768; int rem = slot % 768;
        int dir = rem / 384; rem %= 384;
        int tl = rem / 128; rem %= 128;
        int ks = rem / 64; int LB = rem % 64;
        int row = tl*16 + (LB & 15);
        int k0 = ks*32 + (LB >> 4)*8;
        half8 hv;
        #pragma unroll
        for (int j = 0; j < 8; j++) {
            int k = k0 + j;
            float w = 0.f;
            if (k < 48) w = (dir == 0) ? Wh[L*2304 + row*48 + k] : Wh[L*2304 + k*48 + row];
            hv[j] = (_Float16)w;
        }
        *(half8*)(smem + (L*2+dir)*6144 + (tl*2+ks)*1024 + LB*16) = hv;
    }
    for (int slot = t; slot < 5*64; slot += BLOCK) {
        int which = slot / 64; int LB = slot % 64;
        half8 hv;
        if (which < 2) {          // pred B: ks = which; rows = out class c
            int c = LB & 15; int k0 = which*32 + (LB>>4)*8;
            #pragma unroll
            for (int j = 0; j < 8; j++) { int k = k0+j; hv[j] = (_Float16)((c < 10 && k < 48) ? Wout[c*48+k] : 0.f); }
            *(half8*)(smem + WOUTP_OFF + which*1024 + LB*16) = hv;
        } else {                  // td10 B tiles: rows = hidden comp, K = class (pad 32)
            int tl = which - 2; int row = tl*16 + (LB & 15); int c0 = (LB>>4)*8;
            #pragma unroll
            for (int j = 0; j < 8; j++) { int c = c0+j; hv[j] = (_Float16)((c < 10) ? Wout[c*48+row] : 0.f); }
            *(half8*)(smem + WOUTT_OFF + tl*1024 + LB*16) = hv;
        }
    }
    for (int idx = t; idx < 432; idx += BLOCK) ((float*)(smem+BH_OFF_B))[idx] = bh[idx];
    if (t < 10) ((float*)(smem+BOUT_OFF_B))[t] = bout[t];
    __syncthreads();

    // targets for this lane's 4 samples
    int tg[4];
    #pragma unroll
    for (int r = 0; r < 4; r++) tg[r] = target[bsamp0 + 4*bq + r];

    // ======== forward init layers 1..9 ========
    FWD(1); FWD(2); FWD(3); FWD(4); FWD(5); FWD(6); FWD(7); FWD(8); FWD(9);

    // ======== settling ========
    #pragma unroll 1
    for (int s = 0; s < 20; ++s) {
        float ep[12];
        #pragma unroll
        for (int q = 0; q < 12; q++) ep[q] = v[0][q] - a0r[q];

        LAYER_STEP(1); LAYER_STEP(2); LAYER_STEP(3); LAYER_STEP(4); LAYER_STEP(5);
        LAYER_STEP(6); LAYER_STEP(7); LAYER_STEP(8); LAYER_STEP(9);

        // ---- output layer (all single-f16: LR-damped) ----
        {
            half8 Bp0 = *(const half8*)(smem + WOUTP_OFF + lane*16);
            half8 Bp1 = *(const half8*)(smem + WOUTP_OFF + 1024 + lane*16);
            half8 Bt0 = *(const half8*)(smem + WOUTT_OFF + 0*1024 + lane*16);
            half8 Bt1 = *(const half8*)(smem + WOUTT_OFF + 1*1024 + lane*16);
            half8 Bt2 = *(const half8*)(smem + WOUTT_OFF + 2*1024 + lane*16);
            #pragma unroll
            for (int tt = 0; tt < 3; tt++)
                #pragma unroll
                for (int r = 0; r < 4; r++)
                    vtu[(4*bq+r)*52 + n + 16*tt] = F16BITS(v[9][tt*4+r]) << 16;
            __builtin_amdgcn_fence(__ATOMIC_ACQ_REL, "wavefront");
            half8 Ah0, Ah1;
            {
                const uint32_t* vp = vtu + n*52 + bq*8;
                uint4v wa = *(const uint4v*)vp;
                uint4v wb = *(const uint4v*)(vp + 4);
                uint4v hu; GATHER_HI(wa, wb, hu); Ah0 = __builtin_bit_cast(half8, hu);
                vp = vtu + n*52 + 32 + bq*8;
                wa = *(const uint4v*)vp;
                wb = *(const uint4v*)(vp + 4);
                uint4v hu2; GATHER_HI(wa, wb, hu2); Ah1 = __builtin_bit_cast(half8, hu2);
            }
            float bo = (n < 10) ? boutf[n] : 0.f;
            f32x4 acc = {bo, bo, bo, bo};
            acc = __builtin_amdgcn_mfma_f32_16x16x32_f16(Ah0, Bp0, acc, 0, 0, 0);
            acc = __builtin_amdgcn_mfma_f32_16x16x32_f16(Ah1, Bp1, acc, 0, 0, 0);
            // e10 -> VT cols 0..15 (cols 16..31 stale but finite; B rows c>=10 are zero)
            #pragma unroll
            for (int r = 0; r < 4; r++) {
                float e = 0.f;
                if (n < 10) e = ((n == tg[r]) ? 1.f : 0.f) - acc[r];
                vtu[(4*bq+r)*52 + n] = F16BITS(e) << 16;
            }
            __builtin_amdgcn_fence(__ATOMIC_ACQ_REL, "wavefront");
            half8 eAh;
            {
                const uint32_t* vp = vtu + n*52 + bq*8;
                uint4v wa = *(const uint4v*)vp;
                uint4v wb = *(const uint4v*)(vp + 4);
                uint4v hu; GATHER_HI(wa, wb, hu); eAh = __builtin_bit_cast(half8, hu);
            }
            float td10[12];
            {
                f32x4 a2 = {0.f, 0.f, 0.f, 0.f};
                a2 = __builtin_amdgcn_mfma_f32_16x16x32_f16(eAh, Bt0, a2, 0, 0, 0);
                #pragma unroll
                for (int r = 0; r < 4; r++) td10[r] = a2[r];
            }
            {
                f32x4 a2 = {0.f, 0.f, 0.f, 0.f};
                a2 = __builtin_amdgcn_mfma_f32_16x16x32_f16(eAh, Bt1, a2, 0, 0, 0);
                #pragma unroll
                for (int r = 0; r < 4; r++) td10[4+r] = a2[r];
            }
            {
                f32x4 a2 = {0.f, 0.f, 0.f, 0.f};
                a2 = __builtin_amdgcn_mfma_f32_16x16x32_f16(eAh, Bt2, a2, 0, 0, 0);
                #pragma unroll
                for (int r = 0; r < 4; r++) td10[8+r] = a2[r];
            }
            #pragma unroll
            for (int q = 0; q < 12; q++) {
                float nv = v[9][q] - LR*(ep[q] - td10[q]);
                v[9][q] = fminf(fmaxf(nv, -10.f), 10.f);
            }
        }
    }

    // ======== write V ========
    #pragma unroll
    for (int L2 = 0; L2 < 10; L2++)
        #pragma unroll
        for (int tt = 0; tt < 3; tt++)
            #pragma unroll
            for (int r = 0; r < 4; r++)
                out[(size_t)L2*65536*48 + (size_t)(bsamp0 + 4*bq + r)*48 + n + 16*tt] = v[L2][tt*4+r];
}

extern "C" void kernel_launch(void* const* d_in, const int* in_sizes, int n_in,
                              void* d_out, int out_size, void* d_ws, size_t ws_size,
                              hipStream_t stream) {
    const float* x      = (const float*)d_in[0];
    const int*   target = (const int*)d_in[1];
    const float* W0     = (const float*)d_in[2];
    const float* b0     = (const float*)d_in[3];
    const float* Wh     = (const float*)d_in[4];
    const float* bh     = (const float*)d_in[5];
    const float* Wout   = (const float*)d_in[6];
    const float* bout   = (const float*)d_in[7];
    float* out = (float*)d_out;

    hipFuncSetAttribute((const void*)pcnet_kernel,
                        hipFuncAttributeMaxDynamicSharedMemorySize, LDS_BYTES);

    dim3 grid(65536/128);   // 512 blocks, 128 samples each
    dim3 block(BLOCK);      // 8 waves x 16 samples; 1 block/CU -> 2 waves/SIMD
    pcnet_kernel<<<grid, block, LDS_BYTES, stream>>>(x, target, W0, b0, Wh, bh, Wout, bout, out);
}